// Round 4
// baseline (730.235 us; speedup 1.0000x reference)
//
#include <hip/hip_runtime.h>

#define T 500
#define NB 256
#define VROWS 50001
#define EMB 200
#define KPAD 224
#define MPAD 50048
#define LOG2E 1.44269504f

typedef unsigned short u16;
typedef __attribute__((ext_vector_type(8))) __bf16 bf16x8;
typedef __attribute__((ext_vector_type(8))) short short8;
typedef __attribute__((ext_vector_type(4))) float f32x4;
typedef __attribute__((ext_vector_type(4))) u16 u16x4;
typedef __attribute__((ext_vector_type(4))) int i32x4;

__device__ __forceinline__ u16 f2bf(float x) {
  __bf16 h = (__bf16)x;
  return __builtin_bit_cast(u16, h);
}
__device__ __forceinline__ float bf2f(u16 b) {
  union { unsigned u; float f; } v; v.u = ((unsigned)b) << 16;
  return v.f;
}
__device__ __forceinline__ float rcp_(float x) { return __builtin_amdgcn_rcpf(x); }
__device__ __forceinline__ float ex2_(float x) { return __builtin_amdgcn_exp2f(x); }
// gate scale factors: sig(x)=rcp(1+exp2(-LOG2E*x)); tanh(x)=1-2*rcp(1+exp2(2*LOG2E*x))
__device__ __forceinline__ float gsc(int g) { return (g == 1) ? 2.f * LOG2E : -LOG2E; }

// ---------------------------------------------------------------- prep ------
__global__ void prep_kernel(const int* __restrict__ words, const int* __restrict__ caps,
                            const float* __restrict__ word_emb,
                            const float* __restrict__ cap_emb,
                            const float* __restrict__ Wfw, const float* __restrict__ bfw,
                            const float* __restrict__ Wbw, const float* __restrict__ bbw,
                            int* __restrict__ wordsT, int* __restrict__ capsT,
                            float* __restrict__ Cproj, u16* __restrict__ Apad,
                            u16* __restrict__ Bt) {
  const int S0 = NB * T;
  const int S1 = MPAD * (KPAD / 4);
  const int S2 = 2 * 512 * KPAD;
  const int S3 = 2 * 4 * 512;
  int tid = blockIdx.x * blockDim.x + threadIdx.x;
  int nthr = gridDim.x * blockDim.x;
  for (int i = tid; i < S0 + S1 + S2 + S3; i += nthr) {
    if (i < S0) {
      int b = i / T, t = i - b * T;
      wordsT[t * NB + b] = words[i];
      capsT[t * NB + b]  = caps[i];
    } else if (i < S0 + S1) {
      int idx = i - S0;
      int v = idx / (KPAD / 4), q = idx - v * (KPAD / 4);
      int k = q * 4;
      u16x4 o;
      if (v < VROWS && k < EMB) {
        const float* p = word_emb + (size_t)v * EMB + k;
        o[0] = f2bf(p[0]); o[1] = f2bf(p[1]); o[2] = f2bf(p[2]); o[3] = f2bf(p[3]);
      } else {
        o[0] = o[1] = o[2] = o[3] = 0;
      }
      *(u16x4*)(Apad + (size_t)v * KPAD + k) = o;
    } else if (i < S0 + S1 + S2) {
      int idx = i - S0 - S1;
      int d = idx / (512 * KPAD), rem = idx - d * (512 * KPAD);
      int colp = rem / KPAD, k = rem - colp * KPAD;
      const float* W = d ? Wbw : Wfw;
      int g = colp & 3, jj = colp >> 2;
      Bt[idx] = (k < EMB) ? f2bf(W[k * 512 + g * 128 + jj] * gsc(g)) : (u16)0;
    } else {
      int idx = i - S0 - S1 - S2;
      int dir = idx >> 11; int c = (idx >> 9) & 3; int colp = idx & 511;
      int j = colp >> 2, g = colp & 3;
      const float* W = dir ? Wbw : Wfw;
      const float* bias = dir ? bbw : bfw;
      float v = bias[g * 128 + j] + (g == 2 ? 1.f : 0.f);   // fold forget_bias
      #pragma unroll
      for (int cc = 0; cc < 3; ++cc)
        v += cap_emb[c * 3 + cc] * W[(200 + cc) * 512 + g * 128 + j];
      Cproj[idx] = v * gsc(g);
    }
  }
}

// ------------------------------------------------------------ Vproj GEMM ----
__global__ __launch_bounds__(256) void vproj_kernel(
    const u16* __restrict__ Apad, const u16* __restrict__ Bt,
    u16* __restrict__ Vfw, u16* __restrict__ Vbw) {
  const int mt = blockIdx.x, nt = blockIdx.y, dir = blockIdx.z;
  const u16* __restrict__ B = Bt + (size_t)dir * 512 * KPAD;
  u16* __restrict__ V = dir ? Vbw : Vfw;

  __shared__ u16 Al[2][128 * 32];
  __shared__ u16 Bl[2][128 * 32];

  const int tid = threadIdx.x;
  const int w = tid >> 6, l = tid & 63;
  const int la = l & 15, lb = l >> 4;
  const int m0 = mt * 128, n0 = nt * 128;

  auto stage = [&](int buf, int ks) {
    int k0 = ks * 32;
    #pragma unroll
    for (int h = 0; h < 2; ++h) {
      int c = w * 128 + h * 64 + l;
      int row = c >> 2, kq = c & 3;
      const u16* ga = Apad + (size_t)(m0 + row) * KPAD + k0 + kq * 8;
      __builtin_amdgcn_global_load_lds(
          (const __attribute__((address_space(1))) void*)ga,
          (__attribute__((address_space(3))) void*)&Al[buf][(w * 128 + h * 64) * 8],
          16, 0, 0);
      const u16* gb = B + (size_t)(n0 + row) * KPAD + k0 + kq * 8;
      __builtin_amdgcn_global_load_lds(
          (const __attribute__((address_space(1))) void*)gb,
          (__attribute__((address_space(3))) void*)&Bl[buf][(w * 128 + h * 64) * 8],
          16, 0, 0);
    }
  };

  f32x4 z = {0.f, 0.f, 0.f, 0.f};
  f32x4 acc[4][4] = {{z,z,z,z},{z,z,z,z},{z,z,z,z},{z,z,z,z}};
  const int wr = w >> 1, wc = w & 1;

  stage(0, 0);
  __syncthreads();
  #pragma unroll 1
  for (int ks = 0; ks < 7; ++ks) {
    int cur = ks & 1;
    if (ks < 6) stage(cur ^ 1, ks + 1);
    bf16x8 af[4], bfr[4];
    #pragma unroll
    for (int m = 0; m < 4; ++m)
      af[m] = *(const bf16x8*)&Al[cur][(wr * 64 + m * 16 + la) * 32 + lb * 8];
    #pragma unroll
    for (int n = 0; n < 4; ++n)
      bfr[n] = *(const bf16x8*)&Bl[cur][(wc * 64 + n * 16 + la) * 32 + lb * 8];
    #pragma unroll
    for (int m = 0; m < 4; ++m)
      #pragma unroll
      for (int n = 0; n < 4; ++n)
        acc[m][n] = __builtin_amdgcn_mfma_f32_16x16x32_bf16(af[m], bfr[n], acc[m][n], 0, 0, 0);
    __syncthreads();
  }

  #pragma unroll
  for (int m = 0; m < 4; ++m) {
    #pragma unroll
    for (int n = 0; n < 4; ++n) {
      #pragma unroll
      for (int r = 0; r < 4; ++r) {
        int v = m0 + wr * 64 + m * 16 + lb * 4 + r;
        int colp = n0 + wc * 64 + n * 16 + la;
        V[(size_t)v * 512 + colp] = f2bf(acc[m][n][r]);
      }
    }
  }
}

// ------------------------------------------------------------ LSTM ----------
// M=4 batch rows per block, 128 blocks.  hbuf rows 0-3 live, 4-15 stay zero.
// Swizzle: u16 index ^= (row&7)<<3 on both write and read.
template <int PAR>
__device__ __forceinline__ void lstm_step(
    int t, int dir, int b0, int la, int lb, int j,
    const int* __restrict__ wordsT, const int* __restrict__ capsT,
    const u16* __restrict__ V, const float* __restrict__ Cp,
    const bf16x8 (&bfrag)[4][4], u16* __restrict__ hbuf,
    u16x4 (&vw_c)[4], f32x4 (&cp_c)[4],   // data for t (consume; valid lb==0)
    i32x4& wi_c, i32x4& ci_c,             // slot t: reload with idx(t+4)
    i32x4& wi_g, i32x4& ci_g,             // idx(t+2) (ready)
    u16x4 (&vw_g)[4], f32x4 (&cp_g)[4],   // gather target for t+2
    float& cst, float& hl) {
  // reload (uniform) indices for t+4 into this step's slot
  {
    int ts = t + 4; if (ts > T - 1) ts = T - 1;
    int tt = dir ? (T - 1 - ts) : ts;
    wi_c = *(const i32x4*)(wordsT + tt * NB + b0);
    ci_c = *(const i32x4*)(capsT + tt * NB + b0);
  }
  // issue gathers for t+2 (lb==0 lanes only; others keep zeros)
  if (lb == 0) {
    #pragma unroll
    for (int r = 0; r < 4; ++r) {
      vw_g[r] = *(const u16x4*)(V + (size_t)wi_g[r] * 512 + j * 4);
      cp_g[r] = *(const f32x4*)(Cp + ci_g[r] * 512 + j * 4);
    }
  }

  // A fragments (h_prev) from swizzled LDS
  const u16* hb = hbuf + PAR * 2048;
  const int swz = (la & 7) << 3;
  bf16x8 afr[4];
  #pragma unroll
  for (int kk = 0; kk < 4; ++kk)
    afr[kk] = *(const bf16x8*)(hb + ((la * 128 + kk * 32 + lb * 8) ^ swz));

  // accumulators init with x-projection (+cap+bias); junk-zero in lb!=0 lanes
  f32x4 acc0, acc1, acc2, acc3;
  #pragma unroll
  for (int r = 0; r < 4; ++r) {
    acc0[r] = bf2f(vw_c[r][0]) + cp_c[r][0];
    acc1[r] = bf2f(vw_c[r][1]) + cp_c[r][1];
    acc2[r] = bf2f(vw_c[r][2]) + cp_c[r][2];
    acc3[r] = bf2f(vw_c[r][3]) + cp_c[r][3];
  }
  #pragma unroll
  for (int kk = 0; kk < 4; ++kk) {
    acc0 = __builtin_amdgcn_mfma_f32_16x16x32_bf16(afr[kk], bfrag[0][kk], acc0, 0, 0, 0);
    acc1 = __builtin_amdgcn_mfma_f32_16x16x32_bf16(afr[kk], bfrag[1][kk], acc1, 0, 0, 0);
    acc2 = __builtin_amdgcn_mfma_f32_16x16x32_bf16(afr[kk], bfrag[2][kk], acc2, 0, 0, 0);
    acc3 = __builtin_amdgcn_mfma_f32_16x16x32_bf16(afr[kk], bfrag[3][kk], acc3, 0, 0, 0);
  }

  // redistribute: lane (la,lb) takes gates of cell (row=lb, col=j) from lane la
  float a0, a1, a2, a3;
  #pragma unroll
  for (int r = 0; r < 4; ++r) {
    float t0 = __shfl(acc0[r], la, 64);
    float t1 = __shfl(acc1[r], la, 64);
    float t2 = __shfl(acc2[r], la, 64);
    float t3 = __shfl(acc3[r], la, 64);
    if (lb == r) { a0 = t0; a1 = t1; a2 = t2; a3 = t3; }
  }

  // elementwise (1 cell per lane), pre-scaled gates: sig(x)=rcp(1+exp2(a))
  float ig = rcp_(1.f + ex2_(a0));
  float tj = 1.f - 2.f * rcp_(1.f + ex2_(a1));
  float fg = rcp_(1.f + ex2_(a2));
  float cn = fg * cst + ig * tj;
  cst = cn;
  float og = rcp_(1.f + ex2_(a3));
  float hn = og * (1.f - 2.f * rcp_(1.f + ex2_(2.f * LOG2E * cn)));
  hl = hn;

  // h write: row=lb (0-3), col=j
  u16* ho = hbuf + (PAR ^ 1) * 2048;
  ho[(lb * 128 + j) ^ ((lb & 7) << 3)] = f2bf(hn);

  // LDS-only drain + barrier: global gathers stay in flight
  asm volatile("s_waitcnt lgkmcnt(0)\n\ts_barrier" ::: "memory");
}

__global__ __launch_bounds__(512, 1) void lstm_kernel(
    const int* __restrict__ wordsT, const int* __restrict__ capsT,
    const u16* __restrict__ Vfw, const u16* __restrict__ Vbw,
    const float* __restrict__ CprojAll, const float* __restrict__ Wfw,
    const float* __restrict__ Wbw, float* __restrict__ rnn) {
  const int dir = blockIdx.x & 1;
  const int chunk = blockIdx.x >> 1;
  const int b0 = chunk * 4;
  const u16* __restrict__ V = dir ? Vbw : Vfw;
  const float* __restrict__ Cp = CprojAll + dir * 4 * 512;
  const float* __restrict__ W = dir ? Wbw : Wfw;

  const int tid = threadIdx.x;
  const int w = tid >> 6, l = tid & 63, la = l & 15, lb = l >> 4;
  const int j = w * 16 + la;

  // Wh fragments (pre-scaled): col = g*128 + j, k = kk*32 + lb*8 + r
  bf16x8 bfrag[4][4];
  #pragma unroll
  for (int g = 0; g < 4; ++g) {
    #pragma unroll
    for (int kk = 0; kk < 4; ++kk) {
      short8 t8;
      #pragma unroll
      for (int r = 0; r < 8; ++r) {
        int k = kk * 32 + lb * 8 + r;
        t8[r] = (short)f2bf(W[(203 + k) * 512 + g * 128 + j] * gsc(g));
      }
      bfrag[g][kk] = __builtin_bit_cast(bf16x8, t8);
    }
  }

  __shared__ u16 hbuf[2 * 16 * 128];
  for (int i = tid; i < 2 * 16 * 128; i += 512) hbuf[i] = 0;

  float cst = 0.f, hl = 0.f;

  i32x4 wiA, ciA, wiB, ciB, wiC, ciC, wiD, ciD;
  u16x4 vwA[4], vwB[4], vwC[4], vwD[4];
  f32x4 cpA[4], cpB[4], cpC[4], cpD[4];
  #pragma unroll
  for (int r = 0; r < 4; ++r) {
    vwA[r] = u16x4{0,0,0,0}; vwB[r] = u16x4{0,0,0,0};
    vwC[r] = u16x4{0,0,0,0}; vwD[r] = u16x4{0,0,0,0};
    cpA[r] = f32x4{0,0,0,0}; cpB[r] = f32x4{0,0,0,0};
    cpC[r] = f32x4{0,0,0,0}; cpD[r] = f32x4{0,0,0,0};
  }
  {
    int t0 = dir ? (T - 1) : 0;
    int t1 = dir ? (T - 2) : 1;
    int t2 = dir ? (T - 3) : 2;
    int t3 = dir ? (T - 4) : 3;
    wiA = *(const i32x4*)(wordsT + t0 * NB + b0);
    ciA = *(const i32x4*)(capsT + t0 * NB + b0);
    wiB = *(const i32x4*)(wordsT + t1 * NB + b0);
    ciB = *(const i32x4*)(capsT + t1 * NB + b0);
    wiC = *(const i32x4*)(wordsT + t2 * NB + b0);
    ciC = *(const i32x4*)(capsT + t2 * NB + b0);
    wiD = *(const i32x4*)(wordsT + t3 * NB + b0);
    ciD = *(const i32x4*)(capsT + t3 * NB + b0);
  }
  if (lb == 0) {
    #pragma unroll
    for (int r = 0; r < 4; ++r) {
      vwA[r] = *(const u16x4*)(V + (size_t)wiA[r] * 512 + j * 4);
      cpA[r] = *(const f32x4*)(Cp + ciA[r] * 512 + j * 4);
      vwB[r] = *(const u16x4*)(V + (size_t)wiB[r] * 512 + j * 4);
      cpB[r] = *(const f32x4*)(Cp + ciB[r] * 512 + j * 4);
    }
  }
  __syncthreads();

  #pragma unroll 1
  for (int tq = 0; tq < T / 4; ++tq) {
    int t0 = 4 * tq;
    lstm_step<0>(t0,     dir, b0, la, lb, j, wordsT, capsT, V, Cp, bfrag, hbuf,
                 vwA, cpA, wiA, ciA, wiC, ciC, vwC, cpC, cst, hl);
    lstm_step<1>(t0 + 1, dir, b0, la, lb, j, wordsT, capsT, V, Cp, bfrag, hbuf,
                 vwB, cpB, wiB, ciB, wiD, ciD, vwD, cpD, cst, hl);
    lstm_step<0>(t0 + 2, dir, b0, la, lb, j, wordsT, capsT, V, Cp, bfrag, hbuf,
                 vwC, cpC, wiC, ciC, wiA, ciA, vwA, cpA, cst, hl);
    lstm_step<1>(t0 + 3, dir, b0, la, lb, j, wordsT, capsT, V, Cp, bfrag, hbuf,
                 vwD, cpD, wiD, ciD, wiB, ciB, vwB, cpB, cst, hl);
  }

  // lane (la,lb) holds h_final for (row=b0+lb, col=dir*128+j)
  rnn[(size_t)(b0 + lb) * 256 + dir * 128 + j] = hl;
}

// ------------------------------------------------------------ head ----------
__global__ void head_kernel(const float* __restrict__ rnn, const float* __restrict__ W1,
                            const float* __restrict__ b1, const float* __restrict__ W2,
                            const float* __restrict__ b2, float* __restrict__ out) {
  int b = blockIdx.x;
  int jj = threadIdx.x;  // 64 threads
  __shared__ float d1[64];
  float acc = b1[jj];
  const float* r = rnn + b * 256;
  #pragma unroll 4
  for (int k = 0; k < 256; ++k) acc += r[k] * W1[k * 64 + jj];
  d1[jj] = acc > 0.f ? acc : (__expf(acc) - 1.f);
  __syncthreads();
  if (jj < 6) {
    float a2 = b2[jj];
    #pragma unroll 8
    for (int k = 0; k < 64; ++k) a2 += d1[k] * W2[k * 6 + jj];
    out[b * 6 + jj] = rcp_(1.f + __expf(-a2));
  }
}

// ------------------------------------------------------------ launch --------
extern "C" void kernel_launch(void* const* d_in, const int* in_sizes, int n_in,
                              void* d_out, int out_size, void* d_ws, size_t ws_size,
                              hipStream_t stream) {
  (void)in_sizes; (void)n_in; (void)out_size; (void)ws_size;
  const int*   words    = (const int*)  d_in[0];
  const int*   caps     = (const int*)  d_in[1];
  const float* word_emb = (const float*)d_in[2];
  const float* cap_emb  = (const float*)d_in[3];
  const float* Wfw      = (const float*)d_in[4];
  const float* bfw      = (const float*)d_in[5];
  const float* Wbw      = (const float*)d_in[6];
  const float* bbw      = (const float*)d_in[7];
  const float* W1       = (const float*)d_in[8];
  const float* b1       = (const float*)d_in[9];
  const float* W2       = (const float*)d_in[10];
  const float* b2       = (const float*)d_in[11];
  float* out = (float*)d_out;

  char* base = (char*)d_ws;
  size_t off = 0;
  auto alloc = [&](size_t bytes) {
    char* q = base + off;
    off = (off + bytes + 255) & ~(size_t)255;
    return q;
  };
  u16*   Vfw    = (u16*)  alloc((size_t)MPAD * 512 * 2);
  u16*   Vbw    = (u16*)  alloc((size_t)MPAD * 512 * 2);
  u16*   Apad   = (u16*)  alloc((size_t)MPAD * KPAD * 2);
  u16*   Bt     = (u16*)  alloc((size_t)2 * 512 * KPAD * 2);
  int*   wordsT = (int*)  alloc((size_t)T * NB * 4);
  int*   capsT  = (int*)  alloc((size_t)T * NB * 4);
  float* Cproj  = (float*)alloc((size_t)2 * 4 * 512 * 4);
  float* rnn    = (float*)alloc((size_t)256 * 256 * 4);

  hipLaunchKernelGGL(prep_kernel, dim3(2048), dim3(256), 0, stream,
                     words, caps, word_emb, cap_emb, Wfw, bfw, Wbw, bbw,
                     wordsT, capsT, Cproj, Apad, Bt);
  hipLaunchKernelGGL(vproj_kernel, dim3(MPAD / 128, 4, 2), dim3(256), 0, stream,
                     Apad, Bt, Vfw, Vbw);
  hipLaunchKernelGGL(lstm_kernel, dim3(128), dim3(512), 0, stream,
                     wordsT, capsT, Vfw, Vbw, Cproj, Wfw, Wbw, rnn);
  hipLaunchKernelGGL(head_kernel, dim3(256), dim3(64), 0, stream,
                     rnn, W1, b1, W2, b2, out);
}

// Round 5
// 579.980 us; speedup vs baseline: 1.2591x; 1.2591x over previous
//
#include <hip/hip_runtime.h>

#define T 500
#define NB 256
#define VROWS 50001
#define EMB 200
#define KPAD 224
#define MPAD 50048
#define LOG2E 1.44269504f

typedef unsigned short u16;
typedef __attribute__((ext_vector_type(8))) __bf16 bf16x8;
typedef __attribute__((ext_vector_type(8))) short short8;
typedef __attribute__((ext_vector_type(4))) float f32x4;
typedef __attribute__((ext_vector_type(4))) u16 u16x4;
typedef __attribute__((ext_vector_type(4))) int i32x4;

__device__ __forceinline__ u16 f2bf(float x) {
  __bf16 h = (__bf16)x;
  return __builtin_bit_cast(u16, h);
}
__device__ __forceinline__ float bf2f(u16 b) {
  union { unsigned u; float f; } v; v.u = ((unsigned)b) << 16;
  return v.f;
}
__device__ __forceinline__ float rcp_(float x) { return __builtin_amdgcn_rcpf(x); }
__device__ __forceinline__ float ex2_(float x) { return __builtin_amdgcn_exp2f(x); }
// gate scale factors: sig(x)=rcp(1+exp2(-LOG2E*x)); tanh(x)=1-2*rcp(1+exp2(2*LOG2E*x))
__device__ __forceinline__ float gsc(int g) { return (g == 1) ? 2.f * LOG2E : -LOG2E; }

// ---------------------------------------------------------------- prep ------
__global__ void prep_kernel(const int* __restrict__ words, const int* __restrict__ caps,
                            const float* __restrict__ word_emb,
                            const float* __restrict__ cap_emb,
                            const float* __restrict__ Wfw, const float* __restrict__ bfw,
                            const float* __restrict__ Wbw, const float* __restrict__ bbw,
                            int* __restrict__ wordsT, int* __restrict__ capsT,
                            float* __restrict__ Cproj, u16* __restrict__ Apad,
                            u16* __restrict__ Bt) {
  const int S0 = NB * T;
  const int S1 = MPAD * (KPAD / 4);
  const int S2 = 2 * 512 * KPAD;
  const int S3 = 2 * 4 * 512;
  int tid = blockIdx.x * blockDim.x + threadIdx.x;
  int nthr = gridDim.x * blockDim.x;
  for (int i = tid; i < S0 + S1 + S2 + S3; i += nthr) {
    if (i < S0) {
      int b = i / T, t = i - b * T;
      wordsT[t * NB + b] = words[i];
      capsT[t * NB + b]  = caps[i];
    } else if (i < S0 + S1) {
      int idx = i - S0;
      int v = idx / (KPAD / 4), q = idx - v * (KPAD / 4);
      int k = q * 4;
      u16x4 o;
      if (v < VROWS && k < EMB) {
        const float* p = word_emb + (size_t)v * EMB + k;
        o[0] = f2bf(p[0]); o[1] = f2bf(p[1]); o[2] = f2bf(p[2]); o[3] = f2bf(p[3]);
      } else {
        o[0] = o[1] = o[2] = o[3] = 0;
      }
      *(u16x4*)(Apad + (size_t)v * KPAD + k) = o;
    } else if (i < S0 + S1 + S2) {
      int idx = i - S0 - S1;
      int d = idx / (512 * KPAD), rem = idx - d * (512 * KPAD);
      int colp = rem / KPAD, k = rem - colp * KPAD;
      const float* W = d ? Wbw : Wfw;
      int g = colp & 3, jj = colp >> 2;
      Bt[idx] = (k < EMB) ? f2bf(W[k * 512 + g * 128 + jj] * gsc(g)) : (u16)0;
    } else {
      int idx = i - S0 - S1 - S2;
      int dir = idx >> 11; int c = (idx >> 9) & 3; int colp = idx & 511;
      int j = colp >> 2, g = colp & 3;
      const float* W = dir ? Wbw : Wfw;
      const float* bias = dir ? bbw : bfw;
      float v = bias[g * 128 + j] + (g == 2 ? 1.f : 0.f);   // fold forget_bias
      #pragma unroll
      for (int cc = 0; cc < 3; ++cc)
        v += cap_emb[c * 3 + cc] * W[(200 + cc) * 512 + g * 128 + j];
      Cproj[idx] = v * gsc(g);
    }
  }
}

// ------------------------------------------------------------ Vproj GEMM ----
__global__ __launch_bounds__(256) void vproj_kernel(
    const u16* __restrict__ Apad, const u16* __restrict__ Bt,
    u16* __restrict__ Vfw, u16* __restrict__ Vbw) {
  const int mt = blockIdx.x, nt = blockIdx.y, dir = blockIdx.z;
  const u16* __restrict__ B = Bt + (size_t)dir * 512 * KPAD;
  u16* __restrict__ V = dir ? Vbw : Vfw;

  __shared__ u16 Al[2][128 * 32];
  __shared__ u16 Bl[2][128 * 32];

  const int tid = threadIdx.x;
  const int w = tid >> 6, l = tid & 63;
  const int la = l & 15, lb = l >> 4;
  const int m0 = mt * 128, n0 = nt * 128;

  auto stage = [&](int buf, int ks) {
    int k0 = ks * 32;
    #pragma unroll
    for (int h = 0; h < 2; ++h) {
      int c = w * 128 + h * 64 + l;
      int row = c >> 2, kq = c & 3;
      const u16* ga = Apad + (size_t)(m0 + row) * KPAD + k0 + kq * 8;
      __builtin_amdgcn_global_load_lds(
          (const __attribute__((address_space(1))) void*)ga,
          (__attribute__((address_space(3))) void*)&Al[buf][(w * 128 + h * 64) * 8],
          16, 0, 0);
      const u16* gb = B + (size_t)(n0 + row) * KPAD + k0 + kq * 8;
      __builtin_amdgcn_global_load_lds(
          (const __attribute__((address_space(1))) void*)gb,
          (__attribute__((address_space(3))) void*)&Bl[buf][(w * 128 + h * 64) * 8],
          16, 0, 0);
    }
  };

  f32x4 z = {0.f, 0.f, 0.f, 0.f};
  f32x4 acc[4][4] = {{z,z,z,z},{z,z,z,z},{z,z,z,z},{z,z,z,z}};
  const int wr = w >> 1, wc = w & 1;

  stage(0, 0);
  __syncthreads();
  #pragma unroll 1
  for (int ks = 0; ks < 7; ++ks) {
    int cur = ks & 1;
    if (ks < 6) stage(cur ^ 1, ks + 1);
    bf16x8 af[4], bfr[4];
    #pragma unroll
    for (int m = 0; m < 4; ++m)
      af[m] = *(const bf16x8*)&Al[cur][(wr * 64 + m * 16 + la) * 32 + lb * 8];
    #pragma unroll
    for (int n = 0; n < 4; ++n)
      bfr[n] = *(const bf16x8*)&Bl[cur][(wc * 64 + n * 16 + la) * 32 + lb * 8];
    #pragma unroll
    for (int m = 0; m < 4; ++m)
      #pragma unroll
      for (int n = 0; n < 4; ++n)
        acc[m][n] = __builtin_amdgcn_mfma_f32_16x16x32_bf16(af[m], bfr[n], acc[m][n], 0, 0, 0);
    __syncthreads();
  }

  #pragma unroll
  for (int m = 0; m < 4; ++m) {
    #pragma unroll
    for (int n = 0; n < 4; ++n) {
      #pragma unroll
      for (int r = 0; r < 4; ++r) {
        int v = m0 + wr * 64 + m * 16 + lb * 4 + r;
        int colp = n0 + wc * 64 + n * 16 + la;
        V[(size_t)v * 512 + colp] = f2bf(acc[m][n][r]);
      }
    }
  }
}

// ------------------------------------------------------------ LSTM ----------
// M=16 rows/block, 32 blocks.  hbuf [2][16][128] u16, XOR-swizzled on 16B
// granules: u16 index ^= (row&7)<<3 on both write and read.
// Barrier WITHOUT vmcnt drain: gathers stay in flight across steps.
template <int PAR>
__device__ __forceinline__ void lstm_step(
    int t, int dir, int b0, int la, int lb, int j,
    const int* __restrict__ wordsT, const int* __restrict__ capsT,
    const u16* __restrict__ V, const float* __restrict__ Cp,
    const bf16x8 (&bfrag)[4][4], u16* __restrict__ hbuf,
    u16x4 (&vw_c)[4], f32x4 (&cp_c)[4],   // data for t (consume)
    i32x4& wi_c, i32x4& ci_c,             // slot t: reload with idx(t+4)
    i32x4& wi_g, i32x4& ci_g,             // idx(t+2) (ready)
    u16x4 (&vw_g)[4], f32x4 (&cp_g)[4],   // gather target for t+2
    f32x4& cst, f32x4& hl) {
  // reload indices for t+4 into this step's (now free) slot
  {
    int ts = t + 4; if (ts > T - 1) ts = T - 1;
    int tt = dir ? (T - 1 - ts) : ts;
    wi_c = *(const i32x4*)(wordsT + tt * NB + b0 + lb * 4);
    ci_c = *(const i32x4*)(capsT + tt * NB + b0 + lb * 4);
  }
  // issue gathers for t+2 (2-step prefetch distance)
  #pragma unroll
  for (int r = 0; r < 4; ++r) {
    vw_g[r] = *(const u16x4*)(V + (size_t)wi_g[r] * 512 + j * 4);
    cp_g[r] = *(const f32x4*)(Cp + ci_g[r] * 512 + j * 4);
  }

  // A fragments (h_prev) from swizzled LDS
  const u16* hb = hbuf + PAR * 2048;
  const int swz = (la & 7) << 3;
  bf16x8 afr[4];
  #pragma unroll
  for (int kk = 0; kk < 4; ++kk)
    afr[kk] = *(const bf16x8*)(hb + ((la * 128 + kk * 32 + lb * 8) ^ swz));

  // init accumulators with x-projection (+cap+bias), pre-scaled
  f32x4 acc0, acc1, acc2, acc3;
  #pragma unroll
  for (int r = 0; r < 4; ++r) {
    acc0[r] = bf2f(vw_c[r][0]) + cp_c[r][0];
    acc1[r] = bf2f(vw_c[r][1]) + cp_c[r][1];
    acc2[r] = bf2f(vw_c[r][2]) + cp_c[r][2];
    acc3[r] = bf2f(vw_c[r][3]) + cp_c[r][3];
  }
  // gates += h_prev @ Wh (pre-scaled)
  #pragma unroll
  for (int kk = 0; kk < 4; ++kk) {
    acc0 = __builtin_amdgcn_mfma_f32_16x16x32_bf16(afr[kk], bfrag[0][kk], acc0, 0, 0, 0);
    acc1 = __builtin_amdgcn_mfma_f32_16x16x32_bf16(afr[kk], bfrag[1][kk], acc1, 0, 0, 0);
    acc2 = __builtin_amdgcn_mfma_f32_16x16x32_bf16(afr[kk], bfrag[2][kk], acc2, 0, 0, 0);
    acc3 = __builtin_amdgcn_mfma_f32_16x16x32_bf16(afr[kk], bfrag[3][kk], acc3, 0, 0, 0);
  }
  // cell update; write h_new to other buffer (swizzled)
  u16* ho = hbuf + (PAR ^ 1) * 2048;
  #pragma unroll
  for (int r = 0; r < 4; ++r) {
    float ig = rcp_(1.f + ex2_(acc0[r]));
    float tj = 1.f - 2.f * rcp_(1.f + ex2_(acc1[r]));
    float fg = rcp_(1.f + ex2_(acc2[r]));
    float cn = fg * cst[r] + ig * tj;
    cst[r] = cn;
    float og = rcp_(1.f + ex2_(acc3[r]));
    float hn = og * (1.f - 2.f * rcp_(1.f + ex2_(2.f * LOG2E * cn)));
    hl[r] = hn;
    int row = lb * 4 + r;
    ho[(row * 128 + j) ^ ((row & 7) << 3)] = f2bf(hn);
  }
  // LDS-only drain + raw barrier: vmcnt NOT drained, gathers stay in flight
  __builtin_amdgcn_sched_barrier(0);
  asm volatile("s_waitcnt lgkmcnt(0)");
  __builtin_amdgcn_s_barrier();
  __builtin_amdgcn_sched_barrier(0);
}

__global__ __launch_bounds__(512, 1) void lstm_kernel(
    const int* __restrict__ wordsT, const int* __restrict__ capsT,
    const u16* __restrict__ Vfw, const u16* __restrict__ Vbw,
    const float* __restrict__ CprojAll, const float* __restrict__ Wfw,
    const float* __restrict__ Wbw, float* __restrict__ rnn) {
  const int dir = blockIdx.x & 1;
  const int chunk = blockIdx.x >> 1;
  const int b0 = chunk * 16;
  const u16* __restrict__ V = dir ? Vbw : Vfw;
  const float* __restrict__ Cp = CprojAll + dir * 4 * 512;
  const float* __restrict__ W = dir ? Wbw : Wfw;

  const int tid = threadIdx.x;
  const int w = tid >> 6, l = tid & 63, la = l & 15, lb = l >> 4;
  const int j = w * 16 + la;

  // Wh fragments (pre-scaled): col = g*128 + j, k = kk*32 + lb*8 + r
  bf16x8 bfrag[4][4];
  #pragma unroll
  for (int g = 0; g < 4; ++g) {
    #pragma unroll
    for (int kk = 0; kk < 4; ++kk) {
      short8 t8;
      #pragma unroll
      for (int r = 0; r < 8; ++r) {
        int k = kk * 32 + lb * 8 + r;
        t8[r] = (short)f2bf(W[(203 + k) * 512 + g * 128 + j] * gsc(g));
      }
      bfrag[g][kk] = __builtin_bit_cast(bf16x8, t8);
    }
  }

  __shared__ u16 hbuf[2 * 16 * 128];
  for (int i = tid; i < 2 * 16 * 128; i += 512) hbuf[i] = 0;

  f32x4 cst = {0.f, 0.f, 0.f, 0.f};
  f32x4 hl  = {0.f, 0.f, 0.f, 0.f};

  // 4-slot prefetch ring
  i32x4 wiA, ciA, wiB, ciB, wiC, ciC, wiD, ciD;
  u16x4 vwA[4], vwB[4], vwC[4], vwD[4];
  f32x4 cpA[4], cpB[4], cpC[4], cpD[4];
  {
    int t0 = dir ? (T - 1) : 0;
    int t1 = dir ? (T - 2) : 1;
    int t2 = dir ? (T - 3) : 2;
    int t3 = dir ? (T - 4) : 3;
    wiA = *(const i32x4*)(wordsT + t0 * NB + b0 + lb * 4);
    ciA = *(const i32x4*)(capsT + t0 * NB + b0 + lb * 4);
    wiB = *(const i32x4*)(wordsT + t1 * NB + b0 + lb * 4);
    ciB = *(const i32x4*)(capsT + t1 * NB + b0 + lb * 4);
    wiC = *(const i32x4*)(wordsT + t2 * NB + b0 + lb * 4);
    ciC = *(const i32x4*)(capsT + t2 * NB + b0 + lb * 4);
    wiD = *(const i32x4*)(wordsT + t3 * NB + b0 + lb * 4);
    ciD = *(const i32x4*)(capsT + t3 * NB + b0 + lb * 4);
  }
  #pragma unroll
  for (int r = 0; r < 4; ++r) {
    vwA[r] = *(const u16x4*)(V + (size_t)wiA[r] * 512 + j * 4);
    cpA[r] = *(const f32x4*)(Cp + ciA[r] * 512 + j * 4);
    vwB[r] = *(const u16x4*)(V + (size_t)wiB[r] * 512 + j * 4);
    cpB[r] = *(const f32x4*)(Cp + ciB[r] * 512 + j * 4);
  }
  __syncthreads();

  #pragma unroll 1
  for (int tq = 0; tq < T / 4; ++tq) {
    int t0 = 4 * tq;
    lstm_step<0>(t0,     dir, b0, la, lb, j, wordsT, capsT, V, Cp, bfrag, hbuf,
                 vwA, cpA, wiA, ciA, wiC, ciC, vwC, cpC, cst, hl);
    lstm_step<1>(t0 + 1, dir, b0, la, lb, j, wordsT, capsT, V, Cp, bfrag, hbuf,
                 vwB, cpB, wiB, ciB, wiD, ciD, vwD, cpD, cst, hl);
    lstm_step<0>(t0 + 2, dir, b0, la, lb, j, wordsT, capsT, V, Cp, bfrag, hbuf,
                 vwC, cpC, wiC, ciC, wiA, ciA, vwA, cpA, cst, hl);
    lstm_step<1>(t0 + 3, dir, b0, la, lb, j, wordsT, capsT, V, Cp, bfrag, hbuf,
                 vwD, cpD, wiD, ciD, wiB, ciB, vwB, cpB, cst, hl);
  }

  #pragma unroll
  for (int r = 0; r < 4; ++r)
    rnn[(size_t)(b0 + lb * 4 + r) * 256 + dir * 128 + j] = hl[r];
}

// ------------------------------------------------------------ head ----------
__global__ void head_kernel(const float* __restrict__ rnn, const float* __restrict__ W1,
                            const float* __restrict__ b1, const float* __restrict__ W2,
                            const float* __restrict__ b2, float* __restrict__ out) {
  int b = blockIdx.x;
  int jj = threadIdx.x;  // 64 threads
  __shared__ float d1[64];
  float acc = b1[jj];
  const float* r = rnn + b * 256;
  #pragma unroll 4
  for (int k = 0; k < 256; ++k) acc += r[k] * W1[k * 64 + jj];
  d1[jj] = acc > 0.f ? acc : (__expf(acc) - 1.f);
  __syncthreads();
  if (jj < 6) {
    float a2 = b2[jj];
    #pragma unroll 8
    for (int k = 0; k < 64; ++k) a2 += d1[k] * W2[k * 6 + jj];
    out[b * 6 + jj] = rcp_(1.f + __expf(-a2));
  }
}

// ------------------------------------------------------------ launch --------
extern "C" void kernel_launch(void* const* d_in, const int* in_sizes, int n_in,
                              void* d_out, int out_size, void* d_ws, size_t ws_size,
                              hipStream_t stream) {
  (void)in_sizes; (void)n_in; (void)out_size; (void)ws_size;
  const int*   words    = (const int*)  d_in[0];
  const int*   caps     = (const int*)  d_in[1];
  const float* word_emb = (const float*)d_in[2];
  const float* cap_emb  = (const float*)d_in[3];
  const float* Wfw      = (const float*)d_in[4];
  const float* bfw      = (const float*)d_in[5];
  const float* Wbw      = (const float*)d_in[6];
  const float* bbw      = (const float*)d_in[7];
  const float* W1       = (const float*)d_in[8];
  const float* b1       = (const float*)d_in[9];
  const float* W2       = (const float*)d_in[10];
  const float* b2       = (const float*)d_in[11];
  float* out = (float*)d_out;

  char* base = (char*)d_ws;
  size_t off = 0;
  auto alloc = [&](size_t bytes) {
    char* q = base + off;
    off = (off + bytes + 255) & ~(size_t)255;
    return q;
  };
  u16*   Vfw    = (u16*)  alloc((size_t)MPAD * 512 * 2);
  u16*   Vbw    = (u16*)  alloc((size_t)MPAD * 512 * 2);
  u16*   Apad   = (u16*)  alloc((size_t)MPAD * KPAD * 2);
  u16*   Bt     = (u16*)  alloc((size_t)2 * 512 * KPAD * 2);
  int*   wordsT = (int*)  alloc((size_t)T * NB * 4);
  int*   capsT  = (int*)  alloc((size_t)T * NB * 4);
  float* Cproj  = (float*)alloc((size_t)2 * 4 * 512 * 4);
  float* rnn    = (float*)alloc((size_t)256 * 256 * 4);

  hipLaunchKernelGGL(prep_kernel, dim3(2048), dim3(256), 0, stream,
                     words, caps, word_emb, cap_emb, Wfw, bfw, Wbw, bbw,
                     wordsT, capsT, Cproj, Apad, Bt);
  hipLaunchKernelGGL(vproj_kernel, dim3(MPAD / 128, 4, 2), dim3(256), 0, stream,
                     Apad, Bt, Vfw, Vbw);
  hipLaunchKernelGGL(lstm_kernel, dim3(32), dim3(512), 0, stream,
                     wordsT, capsT, Vfw, Vbw, Cproj, Wfw, Wbw, rnn);
  hipLaunchKernelGGL(head_kernel, dim3(256), dim3(64), 0, stream,
                     rnn, W1, b1, W2, b2, out);
}